// Round 2
// baseline (565.464 us; speedup 1.0000x reference)
//
#include <hip/hip_runtime.h>
#include <stdint.h>

typedef __attribute__((ext_vector_type(8))) short short8;
typedef __attribute__((ext_vector_type(4))) float floatx4;

__device__ __forceinline__ unsigned short f2bf(float x) {
    unsigned int u = __builtin_bit_cast(unsigned int, x);
    unsigned int r = (u + 0x7FFFu + ((u >> 16) & 1u)) >> 16;   // RNE
    return (unsigned short)r;
}

// ---- W f32 -> bf16 (524288 elements, x4 vectorized) ----
__global__ void wconv(const float4* __restrict__ W4, ushort4* __restrict__ Wb4) {
    int i = blockIdx.x * 256 + threadIdx.x;   // 131072 threads
    float4 v = W4[i];
    ushort4 o;
    o.x = f2bf(v.x); o.y = f2bf(v.y); o.z = f2bf(v.z); o.w = f2bf(v.w);
    Wb4[i] = o;
}

// ---- level 0: h0 = bf16(tanh(emb[ids])), [131072][512] ----
__global__ void embed_tanh(const int* __restrict__ ids, const float* __restrict__ emb,
                           ushort* __restrict__ h0) {
    int idx = blockIdx.x * 256 + threadIdx.x;   // 16,777,216 threads
    int e = idx * 4;
    int row = e >> 9;
    int col = e & 511;
    int id = ids[row];
    const float4 v = *reinterpret_cast<const float4*>(emb + (size_t)id * 512 + col);
    ushort4 o;
    o.x = f2bf(tanhf(v.x)); o.y = f2bf(tanhf(v.y));
    o.z = f2bf(tanhf(v.z)); o.w = f2bf(tanhf(v.w));
    *reinterpret_cast<ushort4*>(h0 + e) = o;
}

// ---- one tree level: out[M][512] = tanh(A[M][1024] @ W^T + b) ----
// 128x128 tile, BK=32, double-buffered LDS (T3 2-phase), XOR-swizzled LDS
// (slot ^= (row>>1)&3 per 16B slot; inverse applied to global source col),
// chunked bijective XCD blockIdx swizzle for A-panel L2 reuse.
__global__ __launch_bounds__(256)
void level_gemm(const ushort* __restrict__ A, const ushort* __restrict__ Bt,
                const float* __restrict__ bias,
                ushort* __restrict__ outb, float* __restrict__ outf,
                int M, int last)
{
    // mt/nt decode with XCD chunking (nb % 8 == 0 required for swizzle)
    const int nb  = gridDim.x;
    int bid = blockIdx.x;
    int mt, nt;
    if ((nb & 7) == 0) {
        const int per = nb >> 3;
        const int lin = (bid & 7) * per + (bid >> 3);
        mt = lin >> 2; nt = lin & 3;
    } else {
        mt = bid >> 2; nt = bid & 3;
    }
    const int m0 = mt * 128, n0 = nt * 128;

    __shared__ alignas(16) ushort sA[2][4096];   // [buf][128 rows x 32 elems]
    __shared__ alignas(16) ushort sB[2][4096];

    const int tid  = threadIdx.x;
    const int lane = tid & 63;
    const int w    = tid >> 6;
    const int wr   = w >> 1, wc = w & 1;

    // ---- staging: thread t writes 16B at linear LDS elem t*8 (+2048 for rows 64-127).
    // LDS phys col slot = logical slot ^ ((row>>1)&3)  (involution, mult of 8 elems)
    // so the GLOBAL source column is pre-swizzled with the same XOR.
    const int sr    = tid >> 2;                               // row 0..63
    const int swcol = (((tid & 3) ^ ((tid >> 3) & 3)) << 3);  // swizzled source col (elems)
    const ushort* Ap = A  + (size_t)(m0 + sr) * 1024 + swcol;
    const ushort* Bp = Bt + (size_t)(n0 + sr) * 1024 + swcol;

#define STAGE(buf, k0)                                                          \
    do {                                                                        \
        __builtin_amdgcn_global_load_lds(                                       \
            (const __attribute__((address_space(1))) void*)(Ap + (k0)),         \
            (__attribute__((address_space(3))) void*)&sA[buf][tid * 8], 16, 0, 0); \
        __builtin_amdgcn_global_load_lds(                                       \
            (const __attribute__((address_space(1))) void*)(Ap + 64 * 1024 + (k0)), \
            (__attribute__((address_space(3))) void*)&sA[buf][2048 + tid * 8], 16, 0, 0); \
        __builtin_amdgcn_global_load_lds(                                       \
            (const __attribute__((address_space(1))) void*)(Bp + (k0)),         \
            (__attribute__((address_space(3))) void*)&sB[buf][tid * 8], 16, 0, 0); \
        __builtin_amdgcn_global_load_lds(                                       \
            (const __attribute__((address_space(1))) void*)(Bp + 64 * 1024 + (k0)), \
            (__attribute__((address_space(3))) void*)&sB[buf][2048 + tid * 8], 16, 0, 0); \
    } while (0)

    // ---- fragment read coords (swizzled): row = rA + mi*16, col = kk ^ ((row>>1)&3)<<3
    // (row>>1)&3 == (lane>>1)&3 for all mi since wr*64 and mi*16 are 0 mod 8 rows.
    const int rA   = wr * 64 + (lane & 15);
    const int rB   = wc * 64 + (lane & 15);
    const int kksw = (((lane >> 4) ^ ((lane >> 1) & 3)) << 3);

    floatx4 acc[4][4] = {};

    STAGE(0, 0);
    __syncthreads();   // drains vmcnt(0): buf0 ready

    for (int t = 0; t < 32; ++t) {
        const int cur = t & 1;
        if (t < 31) STAGE(cur ^ 1, (t + 1) * 32);   // prefetch next tile (overlaps compute)

        short8 a[4], bq[4];
        #pragma unroll
        for (int mi = 0; mi < 4; ++mi)
            a[mi] = *reinterpret_cast<const short8*>(&sA[cur][(rA + mi * 16) * 32 + kksw]);
        #pragma unroll
        for (int ni = 0; ni < 4; ++ni)
            bq[ni] = *reinterpret_cast<const short8*>(&sB[cur][(rB + ni * 16) * 32 + kksw]);
        #pragma unroll
        for (int mi = 0; mi < 4; ++mi)
            #pragma unroll
            for (int ni = 0; ni < 4; ++ni)
                acc[mi][ni] = __builtin_amdgcn_mfma_f32_16x16x32_bf16(
                    a[mi], bq[ni], acc[mi][ni], 0, 0, 0);

        __syncthreads();   // drains vmcnt+lgkm: next buf ready, cur buf free to overwrite
    }
#undef STAGE

    // epilogue: D mapping col = lane&15, row = (lane>>4)*4 + j  (m89/m91 verified)
    const int mrow = (lane >> 4) * 4;
    const int ncol = lane & 15;
    #pragma unroll
    for (int mi = 0; mi < 4; ++mi) {
        #pragma unroll
        for (int ni = 0; ni < 4; ++ni) {
            const int n = n0 + wc * 64 + ni * 16 + ncol;
            const float bb = bias[n];
            #pragma unroll
            for (int j = 0; j < 4; ++j) {
                const int m = m0 + wr * 64 + mi * 16 + mrow + j;
                if (m < M) {
                    float v = tanhf(acc[mi][ni][j] + bb);
                    if (last) outf[(size_t)m * 512 + n] = v;
                    else      outb[(size_t)m * 512 + n] = f2bf(v);
                }
            }
        }
    }
}

extern "C" void kernel_launch(void* const* d_in, const int* in_sizes, int n_in,
                              void* d_out, int out_size, void* d_ws, size_t ws_size,
                              hipStream_t stream) {
    const int*   ids  = (const int*)d_in[0];
    const float* emb  = (const float*)d_in[1];
    const float* W    = (const float*)d_in[2];
    const float* bias = (const float*)d_in[3];
    float* out = (float*)d_out;

    // ws layout: Wb (1 MiB) | hA (128 MiB, 131072x512 bf16) | hB (64 MiB)
    unsigned short* Wb = (unsigned short*)d_ws;
    unsigned short* hA = Wb + 524288;
    unsigned short* hB = hA + 67108864;

    wconv<<<512, 256, 0, stream>>>((const float4*)W, (ushort4*)Wb);
    embed_tanh<<<65536, 256, 0, stream>>>(ids, emb, hA);

    int M = 65536;
    for (int l = 1; l <= 11; ++l) {
        const unsigned short* in = (l & 1) ? hA : hB;
        unsigned short*       ob = (l & 1) ? hB : hA;
        int gm = (M + 127) / 128;
        int nb = gm * 4;
        level_gemm<<<nb, 256, 0, stream>>>(in, Wb, bias, ob, out, M, l == 11 ? 1 : 0);
        M >>= 1;
    }
}

// Round 3
// 474.757 us; speedup vs baseline: 1.1911x; 1.1911x over previous
//
#include <hip/hip_runtime.h>
#include <stdint.h>

typedef __attribute__((ext_vector_type(8))) short short8;
typedef __attribute__((ext_vector_type(4))) float floatx4;

__device__ __forceinline__ unsigned short f2bf(float x) {
    unsigned int u = __builtin_bit_cast(unsigned int, x);
    unsigned int r = (u + 0x7FFFu + ((u >> 16) & 1u)) >> 16;   // RNE
    return (unsigned short)r;
}

// tanh = (e^2x - 1)/(e^2x + 1); clamp so e^2x never overflows (tanh(10)=1-4e-9).
// rcp + 1 Newton: rel err ~1e-7, invisible under bf16 rounding. ~9 VALU vs ~30 libm.
__device__ __forceinline__ float fast_tanh(float x) {
    float xc = fminf(fmaxf(x, -10.0f), 10.0f);
    float e  = __expf(2.0f * xc);
    float d  = e + 1.0f;
    float r  = __builtin_amdgcn_rcpf(d);
    r = r * (2.0f - d * r);           // Newton refine
    return (e - 1.0f) * r;
}

// ---- W f32 -> bf16 (524288 elements, x4 vectorized) ----
__global__ void wconv(const float4* __restrict__ W4, ushort4* __restrict__ Wb4) {
    int i = blockIdx.x * 256 + threadIdx.x;   // 131072 threads
    float4 v = W4[i];
    ushort4 o;
    o.x = f2bf(v.x); o.y = f2bf(v.y); o.z = f2bf(v.z); o.w = f2bf(v.w);
    Wb4[i] = o;
}

// ---- level 0: h0 = bf16(tanh(emb[ids])), [131072][512] ----
__global__ void embed_tanh(const int* __restrict__ ids, const float* __restrict__ emb,
                           ushort* __restrict__ h0) {
    int idx = blockIdx.x * 256 + threadIdx.x;   // 16,777,216 threads
    int e = idx * 4;
    int row = e >> 9;
    int col = e & 511;
    int id = ids[row];
    const float4 v = *reinterpret_cast<const float4*>(emb + (size_t)id * 512 + col);
    ushort4 o;
    o.x = f2bf(fast_tanh(v.x)); o.y = f2bf(fast_tanh(v.y));
    o.z = f2bf(fast_tanh(v.z)); o.w = f2bf(fast_tanh(v.w));
    *reinterpret_cast<ushort4*>(h0 + e) = o;
}

// ---- one tree level: out[M][512] = tanh(A[M][1024] @ W^T + b) ----
// 128x128 tile, BK=32, TRIPLE-buffered LDS, stage-2-ahead, ONE raw s_barrier
// per iter + counted vmcnt(4) (T3/T4): prefetched global_load_lds stay in
// flight across barriers. XOR-swizzled LDS (bank-conflict-free), chunked
// bijective XCD blockIdx swizzle.
__global__ __launch_bounds__(256)
void level_gemm(const ushort* __restrict__ A, const ushort* __restrict__ Bt,
                const float* __restrict__ bias,
                ushort* __restrict__ outb, float* __restrict__ outf,
                int M, int last)
{
    const int nb  = gridDim.x;
    int bid = blockIdx.x;
    int mt, nt;
    if ((nb & 7) == 0) {
        const int per = nb >> 3;
        const int lin = (bid & 7) * per + (bid >> 3);
        mt = lin >> 2; nt = lin & 3;
    } else {
        mt = bid >> 2; nt = bid & 3;
    }
    const int m0 = mt * 128, n0 = nt * 128;

    __shared__ alignas(16) ushort sA[3][4096];   // [buf][128 rows x 32 elems]
    __shared__ alignas(16) ushort sB[3][4096];   // 48 KiB total -> 3 blocks/CU

    const int tid  = threadIdx.x;
    const int lane = tid & 63;
    const int w    = tid >> 6;
    const int wr   = w >> 1, wc = w & 1;

    // staging: thread t writes 16B at linear LDS elem t*8 (+2048 for rows 64..127).
    // LDS phys slot = logical slot ^ ((row>>1)&3); inverse applied to global col.
    const int sr    = tid >> 2;
    const int swcol = (((tid & 3) ^ ((tid >> 3) & 3)) << 3);
    const ushort* Ap = A  + (size_t)(m0 + sr) * 1024 + swcol;
    const ushort* Bp = Bt + (size_t)(n0 + sr) * 1024 + swcol;

#define STAGE(buf, k0)                                                          \
    do {                                                                        \
        __builtin_amdgcn_global_load_lds(                                       \
            (const __attribute__((address_space(1))) void*)(Ap + (k0)),         \
            (__attribute__((address_space(3))) void*)&sA[buf][tid * 8], 16, 0, 0); \
        __builtin_amdgcn_global_load_lds(                                       \
            (const __attribute__((address_space(1))) void*)(Ap + 64 * 1024 + (k0)), \
            (__attribute__((address_space(3))) void*)&sA[buf][2048 + tid * 8], 16, 0, 0); \
        __builtin_amdgcn_global_load_lds(                                       \
            (const __attribute__((address_space(1))) void*)(Bp + (k0)),         \
            (__attribute__((address_space(3))) void*)&sB[buf][tid * 8], 16, 0, 0); \
        __builtin_amdgcn_global_load_lds(                                       \
            (const __attribute__((address_space(1))) void*)(Bp + 64 * 1024 + (k0)), \
            (__attribute__((address_space(3))) void*)&sB[buf][2048 + tid * 8], 16, 0, 0); \
    } while (0)

    const int rA   = wr * 64 + (lane & 15);
    const int rB   = wc * 64 + (lane & 15);
    const int kksw = (((lane >> 4) ^ ((lane >> 1) & 3)) << 3);

    floatx4 acc[4][4] = {};

    // Prologue: tiles 0 and 1 in flight.
    STAGE(0, 0);
    STAGE(1, 32);

    int cur = 0, stg = 2;
    for (int t = 0; t < 32; ++t) {
        // Barrier FIRST: guarantees (a) all waves' reads of buf[(t-1)%3] are done
        // before it gets re-staged below; (b) every wave's tile-t loads were
        // retired by its own vmcnt wait in iter t-1, so tile t is fully visible.
        asm volatile("s_barrier" ::: "memory");

        if (t < 30) {
            STAGE(stg, (t + 2) * 32);
            // outstanding: tile t+1 (4) + tile t+2 (4) -> wait to 4 retires t+1.
            asm volatile("s_waitcnt vmcnt(4)" ::: "memory");
            stg = (stg == 2) ? 0 : stg + 1;
        } else {
            asm volatile("s_waitcnt vmcnt(0)" ::: "memory");
        }

        short8 a[4], bq[4];
        #pragma unroll
        for (int mi = 0; mi < 4; ++mi)
            a[mi] = *reinterpret_cast<const short8*>(&sA[cur][(rA + mi * 16) * 32 + kksw]);
        #pragma unroll
        for (int ni = 0; ni < 4; ++ni)
            bq[ni] = *reinterpret_cast<const short8*>(&sB[cur][(rB + ni * 16) * 32 + kksw]);

        __builtin_amdgcn_s_setprio(1);
        #pragma unroll
        for (int mi = 0; mi < 4; ++mi)
            #pragma unroll
            for (int ni = 0; ni < 4; ++ni)
                acc[mi][ni] = __builtin_amdgcn_mfma_f32_16x16x32_bf16(
                    a[mi], bq[ni], acc[mi][ni], 0, 0, 0);
        __builtin_amdgcn_s_setprio(0);

        cur = (cur == 2) ? 0 : cur + 1;
    }
#undef STAGE

    // epilogue: D mapping col = lane&15, row = (lane>>4)*4 + j
    const int mrow = (lane >> 4) * 4;
    const int ncol = lane & 15;
    #pragma unroll
    for (int mi = 0; mi < 4; ++mi) {
        #pragma unroll
        for (int ni = 0; ni < 4; ++ni) {
            const int n = n0 + wc * 64 + ni * 16 + ncol;
            const float bb = bias[n];
            #pragma unroll
            for (int j = 0; j < 4; ++j) {
                const int m = m0 + wr * 64 + mi * 16 + mrow + j;
                if (m < M) {
                    float v = fast_tanh(acc[mi][ni][j] + bb);
                    if (last) outf[(size_t)m * 512 + n] = v;
                    else      outb[(size_t)m * 512 + n] = f2bf(v);
                }
            }
        }
    }
}

extern "C" void kernel_launch(void* const* d_in, const int* in_sizes, int n_in,
                              void* d_out, int out_size, void* d_ws, size_t ws_size,
                              hipStream_t stream) {
    const int*   ids  = (const int*)d_in[0];
    const float* emb  = (const float*)d_in[1];
    const float* W    = (const float*)d_in[2];
    const float* bias = (const float*)d_in[3];
    float* out = (float*)d_out;

    // ws layout: Wb (1 MiB) | hA (128 MiB, 131072x512 bf16) | hB (64 MiB)
    unsigned short* Wb = (unsigned short*)d_ws;
    unsigned short* hA = Wb + 524288;
    unsigned short* hB = hA + 67108864;

    wconv<<<512, 256, 0, stream>>>((const float4*)W, (ushort4*)Wb);
    embed_tanh<<<65536, 256, 0, stream>>>(ids, emb, hA);

    int M = 65536;
    for (int l = 1; l <= 11; ++l) {
        const unsigned short* in = (l & 1) ? hA : hB;
        unsigned short*       ob = (l & 1) ? hB : hA;
        int gm = (M + 127) / 128;
        int nbk = gm * 4;
        level_gemm<<<nbk, 256, 0, stream>>>(in, Wb, bias, ob, out, M, l == 11 ? 1 : 0);
        M >>= 1;
    }
}

// Round 4
// 453.599 us; speedup vs baseline: 1.2466x; 1.0466x over previous
//
#include <hip/hip_runtime.h>
#include <stdint.h>

typedef __attribute__((ext_vector_type(8))) short short8;
typedef __attribute__((ext_vector_type(4))) float floatx4;

__device__ __forceinline__ unsigned short f2bf(float x) {
    unsigned int u = __builtin_bit_cast(unsigned int, x);
    unsigned int r = (u + 0x7FFFu + ((u >> 16) & 1u)) >> 16;   // RNE
    return (unsigned short)r;
}

// tanh = (e^2x-1)/(e^2x+1), clamp |x|<=10; rcp + 1 Newton. ~1e-7 rel err.
__device__ __forceinline__ float fast_tanh(float x) {
    float xc = fminf(fmaxf(x, -10.0f), 10.0f);
    float e  = __expf(2.0f * xc);
    float d  = e + 1.0f;
    float r  = __builtin_amdgcn_rcpf(d);
    r = r * (2.0f - d * r);
    return (e - 1.0f) * r;
}

// ---- W f32 -> bf16 ----
__global__ void wconv(const float4* __restrict__ W4, ushort4* __restrict__ Wb4) {
    int i = blockIdx.x * 256 + threadIdx.x;
    float4 v = W4[i];
    ushort4 o;
    o.x = f2bf(v.x); o.y = f2bf(v.y); o.z = f2bf(v.z); o.w = f2bf(v.w);
    Wb4[i] = o;
}

// ---- level 0: h0 = bf16(tanh(emb[ids])), [131072][512], 8 elems/thread ----
__global__ void embed_tanh(const int* __restrict__ ids, const float* __restrict__ emb,
                           ushort* __restrict__ h0) {
    int idx = blockIdx.x * 256 + threadIdx.x;   // 8,388,608 threads
    int e = idx * 8;
    int row = e >> 9;
    int col = e & 511;
    int id = ids[row];
    const float* src = emb + (size_t)id * 512 + col;
    const float4 v0 = *reinterpret_cast<const float4*>(src);
    const float4 v1 = *reinterpret_cast<const float4*>(src + 4);
    short8 o;
    o[0] = (short)f2bf(fast_tanh(v0.x)); o[1] = (short)f2bf(fast_tanh(v0.y));
    o[2] = (short)f2bf(fast_tanh(v0.z)); o[3] = (short)f2bf(fast_tanh(v0.w));
    o[4] = (short)f2bf(fast_tanh(v1.x)); o[5] = (short)f2bf(fast_tanh(v1.y));
    o[6] = (short)f2bf(fast_tanh(v1.z)); o[7] = (short)f2bf(fast_tanh(v1.w));
    *reinterpret_cast<short8*>(h0 + e) = o;
}

// ---- levels 1..5: out[M][512] = tanh(A[M][1024] @ W^T + b), M >= 4096 ----
// 128x128 tile, BK=32, triple-buffered LDS, stage-2-ahead, counted vmcnt(4),
// K-loop unrolled x3 so all buffer indices are compile-time (static LDS bases).
__global__ __launch_bounds__(256)
void level_gemm(const ushort* __restrict__ A, const ushort* __restrict__ Bt,
                const float* __restrict__ bias,
                ushort* __restrict__ outb, int M)
{
    const int nb  = gridDim.x;
    int bid = blockIdx.x;
    const int per = nb >> 3;                       // nb always multiple of 8 here
    const int lin = (bid & 7) * per + (bid >> 3);  // bijective XCD chunking
    const int mt = lin >> 2, nt = lin & 3;
    const int m0 = mt * 128, n0 = nt * 128;

    __shared__ alignas(16) ushort sA[3][4096];
    __shared__ alignas(16) ushort sB[3][4096];

    const int tid  = threadIdx.x;
    const int lane = tid & 63;
    const int w    = tid >> 6;
    const int wr   = w >> 1, wc = w & 1;

    const int sr    = tid >> 2;
    const int swcol = (((tid & 3) ^ ((tid >> 3) & 3)) << 3);
    const ushort* Ap = A  + (size_t)(m0 + sr) * 1024 + swcol;
    const ushort* Bp = Bt + (size_t)(n0 + sr) * 1024 + swcol;

#define STAGE(buf, k0)                                                          \
    do {                                                                        \
        __builtin_amdgcn_global_load_lds(                                       \
            (const __attribute__((address_space(1))) void*)(Ap + (k0)),         \
            (__attribute__((address_space(3))) void*)&sA[buf][tid * 8], 16, 0, 0); \
        __builtin_amdgcn_global_load_lds(                                       \
            (const __attribute__((address_space(1))) void*)(Ap + 64 * 1024 + (k0)), \
            (__attribute__((address_space(3))) void*)&sA[buf][2048 + tid * 8], 16, 0, 0); \
        __builtin_amdgcn_global_load_lds(                                       \
            (const __attribute__((address_space(1))) void*)(Bp + (k0)),         \
            (__attribute__((address_space(3))) void*)&sB[buf][tid * 8], 16, 0, 0); \
        __builtin_amdgcn_global_load_lds(                                       \
            (const __attribute__((address_space(1))) void*)(Bp + 64 * 1024 + (k0)), \
            (__attribute__((address_space(3))) void*)&sB[buf][2048 + tid * 8], 16, 0, 0); \
    } while (0)

    const int rA   = wr * 64 + (lane & 15);
    const int rB   = wc * 64 + (lane & 15);
    const int kksw = (((lane >> 4) ^ ((lane >> 1) & 3)) << 3);

    floatx4 acc[4][4] = {};

#define COMPUTE(cur)                                                            \
    do {                                                                        \
        short8 a_[4], b_[4];                                                    \
        _Pragma("unroll")                                                       \
        for (int mi = 0; mi < 4; ++mi)                                          \
            a_[mi] = *reinterpret_cast<const short8*>(&sA[cur][(rA + mi * 16) * 32 + kksw]); \
        _Pragma("unroll")                                                       \
        for (int ni = 0; ni < 4; ++ni)                                          \
            b_[ni] = *reinterpret_cast<const short8*>(&sB[cur][(rB + ni * 16) * 32 + kksw]); \
        __builtin_amdgcn_s_setprio(1);                                          \
        _Pragma("unroll")                                                       \
        for (int mi = 0; mi < 4; ++mi)                                          \
            _Pragma("unroll")                                                   \
            for (int ni = 0; ni < 4; ++ni)                                      \
                acc[mi][ni] = __builtin_amdgcn_mfma_f32_16x16x32_bf16(          \
                    a_[mi], b_[ni], acc[mi][ni], 0, 0, 0);                      \
        __builtin_amdgcn_s_setprio(0);                                          \
    } while (0)

#define ITER_S(cur, stg, tile)                                                  \
    do {                                                                        \
        asm volatile("s_barrier" ::: "memory");                                 \
        STAGE(stg, (tile) * 32);                                                \
        asm volatile("s_waitcnt vmcnt(4)" ::: "memory");                        \
        COMPUTE(cur);                                                           \
    } while (0)

#define ITER_D(cur)                                                             \
    do {                                                                        \
        asm volatile("s_barrier" ::: "memory");                                 \
        asm volatile("s_waitcnt vmcnt(0)" ::: "memory");                        \
        COMPUTE(cur);                                                           \
    } while (0)

    // Prologue: tiles 0,1 in flight. Ledger identical to round 3 (validated):
    // barrier-first guarantees prior-buf readers done + own tile-t loads retired.
    STAGE(0, 0);
    STAGE(1, 32);
    for (int t = 0; t < 30; t += 3) {   // iters 0..29, cur = t%3, stage tile t+2
        ITER_S(0, 2, t + 2);
        ITER_S(1, 0, t + 3);
        ITER_S(2, 1, t + 4);
    }
    ITER_D(0);   // iter 30
    ITER_D(1);   // iter 31
#undef ITER_S
#undef ITER_D
#undef COMPUTE
#undef STAGE

    const int mrow = (lane >> 4) * 4;
    const int ncol = lane & 15;
    #pragma unroll
    for (int mi = 0; mi < 4; ++mi) {
        #pragma unroll
        for (int ni = 0; ni < 4; ++ni) {
            const int n = n0 + wc * 64 + ni * 16 + ncol;
            const float bb = bias[n];
            #pragma unroll
            for (int j = 0; j < 4; ++j) {
                const int m = m0 + wr * 64 + mi * 16 + mrow + j;
                float v = fast_tanh(acc[mi][ni][j] + bb);
                outb[(size_t)m * 512 + n] = f2bf(v);
            }
        }
    }
}

// ---- levels 6..11 fused: one block per tree ----
// Input: level-5 h [4096][512] bf16 (64 rows/tree). Per level (M_tree =
// 32,16,8,4,2,1): out = tanh(A[M][1024] @ W^T + b); h kept in XOR-swizzled LDS,
// W streamed from L2 straight into B-fragments (reg double-buffered).
__global__ __launch_bounds__(512)
void tail_levels(const ushort* __restrict__ h5, const ushort* __restrict__ Wb,
                 const float* __restrict__ bias, float* __restrict__ out)
{
    __shared__ alignas(16) ushort bufA[64 * 512];   // 64 KiB
    __shared__ alignas(16) ushort bufB[32 * 512];   // 32 KiB

    const int tid  = threadIdx.x;
    const int lane = tid & 63;
    const int wv   = tid >> 6;          // 0..7, N-slice wv*64
    const int tree = blockIdx.x;

    // swizzle: elem (r,c) stored at r*512 + ((c>>3 ^ ((r>>1)&7))<<3) + (c&7)
    // prologue: load this tree's 64 rows into bufA (swizzled)
    #pragma unroll
    for (int i = 0; i < 8; ++i) {
        int ci = i * 512 + tid;         // 4096 16B-chunks
        int r = ci >> 6, s = ci & 63;
        short8 v = *reinterpret_cast<const short8*>(
            &h5[(size_t)(tree * 64 + r) * 512 + (s << 3)]);
        *reinterpret_cast<short8*>(&bufA[r * 512 + ((s ^ ((r >> 1) & 7)) << 3)]) = v;
    }
    __syncthreads();

    // per-lane B pointer: row = wv*64 + ni*16 + (lane&15), k-off = (lane>>4)*8
    const ushort* Wl = Wb + (size_t)(wv * 64 + (lane & 15)) * 1024 + ((lane >> 4) << 3);
    float bb[4];
    #pragma unroll
    for (int ni = 0; ni < 4; ++ni) bb[ni] = bias[wv * 64 + ni * 16 + (lane & 15)];

    const ushort* src = bufA;
    ushort*       dst = bufB;
    int M = 32;
    for (int lev = 0; lev < 6; ++lev, M >>= 1) {
        const int Mtiles = (M > 16) ? 2 : 1;
        floatx4 acc[2][4] = {};
        short8 bc[4], bn[4];
        #pragma unroll
        for (int ni = 0; ni < 4; ++ni)
            bc[ni] = *reinterpret_cast<const short8*>(&Wl[ni * 16384]);

        for (int t = 0; t < 32; ++t) {
            const int k0 = t * 32;
            if (t < 31) {
                #pragma unroll
                for (int ni = 0; ni < 4; ++ni)
                    bn[ni] = *reinterpret_cast<const short8*>(&Wl[ni * 16384 + k0 + 32]);
            }
            short8 a_[2];
            #pragma unroll
            for (int mi = 0; mi < 2; ++mi) {
                if (mi < Mtiles) {
                    int m = mi * 16 + (lane & 15);
                    int r = 2 * m + (k0 >> 9);
                    int c = (k0 & 511) + ((lane >> 4) << 3);
                    a_[mi] = *reinterpret_cast<const short8*>(
                        &src[r * 512 + ((((c >> 3) ^ ((r >> 1) & 7))) << 3)]);
                }
            }
            #pragma unroll
            for (int mi = 0; mi < 2; ++mi)
                if (mi < Mtiles) {
                    #pragma unroll
                    for (int ni = 0; ni < 4; ++ni)
                        acc[mi][ni] = __builtin_amdgcn_mfma_f32_16x16x32_bf16(
                            a_[mi], bc[ni], acc[mi][ni], 0, 0, 0);
                }
            #pragma unroll
            for (int ni = 0; ni < 4; ++ni) bc[ni] = bn[ni];
        }

        // epilogue: D row=(lane>>4)*4+j (+mi*16), col=wv*64+ni*16+(lane&15)
        #pragma unroll
        for (int mi = 0; mi < 2; ++mi) {
            if (mi < Mtiles) {
                #pragma unroll
                for (int ni = 0; ni < 4; ++ni) {
                    const int col = wv * 64 + ni * 16 + (lane & 15);
                    #pragma unroll
                    for (int j = 0; j < 4; ++j) {
                        const int row = mi * 16 + (lane >> 4) * 4 + j;
                        if (row < M) {
                            float v = fast_tanh(acc[mi][ni][j] + bb[ni]);
                            if (lev == 5) {
                                out[(size_t)tree * 512 + col] = v;   // root row (row==0)
                            } else {
                                dst[row * 512 + (((col >> 3) ^ ((row >> 1) & 7)) << 3)
                                    + (col & 7)] = f2bf(v);
                            }
                        }
                    }
                }
            }
        }
        __syncthreads();
        const ushort* ns = dst; dst = const_cast<ushort*>(src); src = ns;
    }
}

extern "C" void kernel_launch(void* const* d_in, const int* in_sizes, int n_in,
                              void* d_out, int out_size, void* d_ws, size_t ws_size,
                              hipStream_t stream) {
    const int*   ids  = (const int*)d_in[0];
    const float* emb  = (const float*)d_in[1];
    const float* W    = (const float*)d_in[2];
    const float* bias = (const float*)d_in[3];
    float* out = (float*)d_out;

    unsigned short* Wb = (unsigned short*)d_ws;        // 1 MiB
    unsigned short* hA = Wb + 524288;                  // 128 MiB
    unsigned short* hB = hA + 67108864;                // 64 MiB

    wconv<<<512, 256, 0, stream>>>((const float4*)W, (ushort4*)Wb);
    embed_tanh<<<32768, 256, 0, stream>>>(ids, emb, hA);

    int M = 65536;
    for (int l = 1; l <= 5; ++l) {                     // outputs: hB,hA,hB,hA,hB
        const unsigned short* in = (l & 1) ? hA : hB;
        unsigned short*       ob = (l & 1) ? hB : hA;
        int gm = M / 128;
        level_gemm<<<gm * 4, 256, 0, stream>>>(in, Wb, bias, ob, M);
        M >>= 1;
    }
    tail_levels<<<64, 512, 0, stream>>>(hB, Wb, bias, out);   // levels 6..11
}